// Round 1
// baseline (8983.992 us; speedup 1.0000x reference)
//
#include <hip/hip_runtime.h>
#include <math.h>

#define Bv    4096
#define Tv    24
#define Nv    7
#define DYNv  6
#define STATv 5
#define INv   11
#define Hv    64
#define HH    32
#define FUTv  48
#define BBv   4
#define Rv    28      // BBv * Nv rows per block
#define RHv   14      // rows per gate-thread (half of Rv)
#define NT    512

__global__ __launch_bounds__(NT, 2)
void stgnn(const float* __restrict__ xh,   const float* __restrict__ adj,
           const float* __restrict__ encw, const float* __restrict__ encb,
           const float* __restrict__ g1w,  const float* __restrict__ g1b,
           const float* __restrict__ g2w,  const float* __restrict__ g2b,
           const float* __restrict__ wih,  const float* __restrict__ whh,
           const float* __restrict__ bih,  const float* __restrict__ bhh,
           const float* __restrict__ d1w,  const float* __restrict__ d1b,
           const float* __restrict__ d2w,  const float* __restrict__ d2b,
           float* __restrict__ out)
{
    // ---- LDS ----
    __shared__ float sWenc[INv][Hv];
    __shared__ float sBenc[Hv];
    __shared__ float sWg1[Hv][Hv];
    __shared__ float sBg1[Hv];
    __shared__ float sWg2[Hv][Hv];
    __shared__ float sBg2[Hv];
    __shared__ float sWd1[Hv][HH];
    __shared__ float sBd1[HH];
    __shared__ float sWd2[HH][DYNv];
    __shared__ float sBd2[DYNv];
    __shared__ float sAdj[BBv][Nv][Nv];
    __shared__ float sDeg[BBv][Nv];
    __shared__ float sXT[Rv][INv];        // x_t staging [r][f]
    __shared__ float sB0[Hv][Rv];         // activations transposed [k][r]
    __shared__ float sB1[Hv][Rv];
    __shared__ float sHX[Hv][Rv];         // hx transposed [h][r]
    __shared__ float sGA[4*Hv][Rv+1];     // activated gates [c][r], stride 29 (bank-conflict pad)
    __shared__ float sD1[HH][Rv];         // decoder hidden transposed [j][r]
    __shared__ float sPRED[Rv][DYNv];
    __shared__ float sSTAT[Rv][STATv];

    const int tid  = threadIdx.x;
    const int lane = tid & 63;
    const int wv   = tid >> 6;            // wave id 0..7
    const int b0   = blockIdx.x * BBv;

    // ---- stage weights into LDS (once) ----
    for (int i = tid; i < INv*Hv; i += NT) ((float*)sWenc)[i] = encw[i];
    if (tid < Hv) sBenc[tid] = encb[tid];
    for (int i = tid; i < Hv*Hv; i += NT) ((float*)sWg1)[i] = g1w[i];
    if (tid < Hv) sBg1[tid] = g1b[tid];
    for (int i = tid; i < Hv*Hv; i += NT) ((float*)sWg2)[i] = g2w[i];
    if (tid < Hv) sBg2[tid] = g2b[tid];
    for (int i = tid; i < Hv*HH; i += NT) ((float*)sWd1)[i] = d1w[i];
    if (tid < HH) sBd1[tid] = d1b[tid];
    for (int i = tid; i < HH*DYNv; i += NT) ((float*)sWd2)[i] = d2w[i];
    if (tid < DYNv) sBd2[tid] = d2b[tid];

    // ---- gate weights -> registers: thread owns gate column gc, row-half `half`
    const int gc   = tid & 255;
    const int half = tid >> 8;            // 0 or 1
    const int rb   = half * RHv;
    float rwi[Hv], rwh[Hv];
    {
        const float4* p1 = (const float4*)(wih + (size_t)gc * Hv);
        const float4* p2 = (const float4*)(whh + (size_t)gc * Hv);
        #pragma unroll
        for (int q = 0; q < Hv/4; ++q) {
            float4 a = p1[q], b = p2[q];
            rwi[4*q+0]=a.x; rwi[4*q+1]=a.y; rwi[4*q+2]=a.z; rwi[4*q+3]=a.w;
            rwh[4*q+0]=b.x; rwh[4*q+1]=b.y; rwh[4*q+2]=b.z; rwh[4*q+3]=b.w;
        }
    }
    const float gbias = bih[gc] + bhh[gc];

    // ---- adjacency normalization (per batch) ----
    if (tid < BBv*Nv*Nv) {
        int bb = tid / (Nv*Nv), rm = tid % (Nv*Nv), i = rm / Nv, j = rm % Nv;
        float a = adj[(size_t)(b0+bb)*Nv*Nv + rm];
        if (i == j) a = 1.0f;
        sAdj[bb][i][j] = a;
    }
    __syncthreads();
    if (tid < BBv*Nv) {
        int bb = tid / Nv, i = tid % Nv;
        float s = 0.f;
        #pragma unroll
        for (int j = 0; j < Nv; ++j) s += sAdj[bb][i][j];
        s = fmaxf(s, 1.0f);
        sDeg[bb][i] = 1.0f / sqrtf(s);
    }
    __syncthreads();
    if (tid < BBv*Nv*Nv) {
        int bb = tid / (Nv*Nv), rm = tid % (Nv*Nv), i = rm / Nv, j = rm % Nv;
        sAdj[bb][i][j] *= sDeg[bb][i] * sDeg[bb][j];
    }
    // zero hx
    for (int i = tid; i < Hv*Rv; i += NT) ((float*)sHX)[i] = 0.f;

    // fixed thread -> row mapping for the H-wide stages (h = lane, rows wv + 8j)
    int rr[4]; bool rok[4]; int rbb[4], rnn[4];
    #pragma unroll
    for (int j = 0; j < 4; ++j) {
        rr[j]  = wv + 8*j;
        rok[j] = rr[j] < Rv;
        rbb[j] = rok[j] ? rr[j] / Nv : 0;
        rnn[j] = rok[j] ? rr[j] % Nv : 0;
    }
    float rcx[4] = {0.f, 0.f, 0.f, 0.f};
    __syncthreads();

    // ---- one LSTM-GCN cell step (consumes sXT, updates sHX + rcx) ----
    auto cell = [&]() {
        // encoder: relu(x @ enc_w + enc_b) -> sB0
        {
            float acc[4];
            float bz = sBenc[lane];
            #pragma unroll
            for (int j = 0; j < 4; ++j) acc[j] = bz;
            #pragma unroll
            for (int f = 0; f < INv; ++f) {
                float w = sWenc[f][lane];
                #pragma unroll
                for (int j = 0; j < 4; ++j)
                    if (rok[j]) acc[j] = fmaf(sXT[rr[j]][f], w, acc[j]);
            }
            #pragma unroll
            for (int j = 0; j < 4; ++j)
                if (rok[j]) sB0[lane][rr[j]] = fmaxf(acc[j], 0.f);
        }
        __syncthreads();
        // gcn1 matmul: sB1 = sB0^T @ Wg1 (stored transposed)
        {
            float acc[4] = {0.f,0.f,0.f,0.f};
            #pragma unroll 8
            for (int k = 0; k < Hv; ++k) {
                float w = sWg1[k][lane];
                #pragma unroll
                for (int j = 0; j < 4; ++j)
                    if (rok[j]) acc[j] = fmaf(sB0[k][rr[j]], w, acc[j]);
            }
            #pragma unroll
            for (int j = 0; j < 4; ++j)
                if (rok[j]) sB1[lane][rr[j]] = acc[j];
        }
        __syncthreads();
        // gcn1 mix: relu(adjn @ y + b) -> sB0
        {
            #pragma unroll
            for (int j = 0; j < 4; ++j) if (rok[j]) {
                float a = sBg1[lane];
                #pragma unroll
                for (int q = 0; q < Nv; ++q)
                    a = fmaf(sAdj[rbb[j]][rnn[j]][q], sB1[lane][rbb[j]*Nv + q], a);
                sB0[lane][rr[j]] = fmaxf(a, 0.f);
            }
        }
        __syncthreads();
        // gcn2 matmul -> sB1
        {
            float acc[4] = {0.f,0.f,0.f,0.f};
            #pragma unroll 8
            for (int k = 0; k < Hv; ++k) {
                float w = sWg2[k][lane];
                #pragma unroll
                for (int j = 0; j < 4; ++j)
                    if (rok[j]) acc[j] = fmaf(sB0[k][rr[j]], w, acc[j]);
            }
            #pragma unroll
            for (int j = 0; j < 4; ++j)
                if (rok[j]) sB1[lane][rr[j]] = acc[j];
        }
        __syncthreads();
        // gcn2 mix -> sB0 (= s, LSTM input)
        {
            #pragma unroll
            for (int j = 0; j < 4; ++j) if (rok[j]) {
                float a = sBg2[lane];
                #pragma unroll
                for (int q = 0; q < Nv; ++q)
                    a = fmaf(sAdj[rbb[j]][rnn[j]][q], sB1[lane][rbb[j]*Nv + q], a);
                sB0[lane][rr[j]] = fmaxf(a, 0.f);
            }
        }
        __syncthreads();
        // gates: g[r][gc] = s@w_ih^T + hx@w_hh^T + b  (weights in registers)
        {
            float acc[RHv];
            #pragma unroll
            for (int r = 0; r < RHv; ++r) acc[r] = gbias;
            #pragma unroll
            for (int k = 0; k < Hv; ++k) {
                float wi = rwi[k], wh = rwh[k];
                #pragma unroll
                for (int r = 0; r < RHv; ++r)
                    acc[r] = fmaf(sB0[k][rb+r], wi, fmaf(sHX[k][rb+r], wh, acc[r]));
            }
            if ((gc >> 6) == 2) {            // g-gate -> tanh (wave-uniform branch)
                #pragma unroll
                for (int r = 0; r < RHv; ++r) sGA[gc][rb+r] = tanhf(acc[r]);
            } else {                          // i, f, o -> sigmoid
                #pragma unroll
                for (int r = 0; r < RHv; ++r) sGA[gc][rb+r] = 1.0f/(1.0f + __expf(-acc[r]));
            }
        }
        __syncthreads();
        // LSTM pointwise: cx in registers, hx -> LDS
        {
            #pragma unroll
            for (int j = 0; j < 4; ++j) if (rok[j]) {
                int r = rr[j];
                float iv = sGA[lane][r];
                float fv = sGA[Hv + lane][r];
                float gv = sGA[2*Hv + lane][r];
                float ov = sGA[3*Hv + lane][r];
                float c  = fmaf(fv, rcx[j], iv * gv);
                rcx[j]   = c;
                sHX[lane][r] = ov * tanhf(c);
            }
        }
        __syncthreads();
    };

    // ---- history scan ----
    for (int t = 0; t < Tv; ++t) {
        for (int idx = tid; idx < Rv*INv; idx += NT) {
            int r = idx / INv, f = idx % INv;
            int bb = r / Nv, n = r % Nv;
            sXT[r][f] = xh[(((size_t)(b0+bb)*Tv + t)*Nv + n)*INv + f];
        }
        __syncthreads();
        cell();
    }

    // init pred/stat from last history step (still resident in sXT)
    for (int idx = tid; idx < Rv*INv; idx += NT) {
        int r = idx / INv, f = idx % INv;
        float v = sXT[r][f];
        if (f < DYNv) sPRED[r][f] = v; else sSTAT[r][f - DYNv] = v;
    }
    __syncthreads();

    // ---- autoregressive future scan ----
    for (int st = 0; st < FUTv; ++st) {
        for (int idx = tid; idx < Rv*INv; idx += NT) {
            int r = idx / INv, f = idx % INv;
            sXT[r][f] = (f < DYNv) ? sPRED[r][f] : sSTAT[r][f - DYNv];
        }
        __syncthreads();
        cell();
        // decoder layer 1: relu(hx @ dec_w1 + b1) -> sD1
        {
            int dj = tid & (HH-1), dg = tid >> 5;   // dg 0..15
            #pragma unroll
            for (int m = 0; m < 2; ++m) {
                int r = dg + 16*m;
                if (r < Rv) {
                    float a = sBd1[dj];
                    #pragma unroll 8
                    for (int k = 0; k < Hv; ++k)
                        a = fmaf(sHX[k][r], sWd1[k][dj], a);
                    sD1[dj][r] = fmaxf(a, 0.f);
                }
            }
        }
        __syncthreads();
        // decoder layer 2 + residual update + store
        if (tid < Rv*DYNv) {
            int r = tid / DYNv, d = tid % DYNv;
            float a = sBd2[d];
            #pragma unroll
            for (int k = 0; k < HH; ++k)
                a = fmaf(sD1[k][r], sWd2[k][d], a);
            float p = sPRED[r][d] + tanhf(a) * 0.05f;
            p = fminf(fmaxf(p, 0.f), 1.f);
            sPRED[r][d] = p;
            out[(((size_t)(b0 + r/Nv) * FUTv + st) * Nv + (r % Nv)) * DYNv + d] = p;
        }
        __syncthreads();
    }
}

extern "C" void kernel_launch(void* const* d_in, const int* in_sizes, int n_in,
                              void* d_out, int out_size, void* d_ws, size_t ws_size,
                              hipStream_t stream)
{
    const float* xh   = (const float*)d_in[0];
    const float* adjp = (const float*)d_in[1];
    const float* encw = (const float*)d_in[2];
    const float* encb = (const float*)d_in[3];
    const float* g1w  = (const float*)d_in[4];
    const float* g1b  = (const float*)d_in[5];
    const float* g2w  = (const float*)d_in[6];
    const float* g2b  = (const float*)d_in[7];
    const float* wih  = (const float*)d_in[8];
    const float* whh  = (const float*)d_in[9];
    const float* bih  = (const float*)d_in[10];
    const float* bhh  = (const float*)d_in[11];
    const float* d1w  = (const float*)d_in[12];
    const float* d1b  = (const float*)d_in[13];
    const float* d2w  = (const float*)d_in[14];
    const float* d2b  = (const float*)d_in[15];
    float* out = (float*)d_out;

    hipLaunchKernelGGL(stgnn, dim3(Bv/BBv), dim3(NT), 0, stream,
                       xh, adjp, encw, encb, g1w, g1b, g2w, g2b,
                       wih, whh, bih, bhh, d1w, d1b, d2w, d2b, out);
}

// Round 2
// 4621.666 us; speedup vs baseline: 1.9439x; 1.9439x over previous
//
#include <hip/hip_runtime.h>
#include <math.h>

#define NT    512
#define NWAVE 8
#define GRID  512   // 4096 batches / 8 per block

__device__ __forceinline__ float rdl(float v, int l) {
    return __uint_as_float(__builtin_amdgcn_readlane(__float_as_uint(v), l));
}
__device__ __forceinline__ float sigm(float x) { return 1.0f / (1.0f + __expf(-x)); }
__device__ __forceinline__ float tanh_f(float x) {
    return 1.0f - 2.0f / (__expf(2.0f * x) + 1.0f);
}
// wave-local LDS write->read ordering: DS pipe is in-order per wave; the waitcnt +
// memory clobber stop both HW in-flight and compiler reordering.
#define WFENCE() asm volatile("s_waitcnt lgkmcnt(0)" ::: "memory")

__global__ __launch_bounds__(NT, 2)
void stgnn(const float* __restrict__ xh,   const float* __restrict__ adj,
           const float* __restrict__ encw, const float* __restrict__ encb,
           const float* __restrict__ g1w,  const float* __restrict__ g1b,
           const float* __restrict__ g2w,  const float* __restrict__ g2b,
           const float* __restrict__ wih,  const float* __restrict__ whh,
           const float* __restrict__ bih,  const float* __restrict__ bhh,
           const float* __restrict__ d1w,  const float* __restrict__ d1b,
           const float* __restrict__ d2w,  const float* __restrict__ d2b,
           float* __restrict__ out)
{
    // gate weights, shared by all waves: [k][h*4+gate], b128 per lane, conflict-free
    __shared__ __align__(16) float sWI[64 * 256];
    __shared__ __align__(16) float sWH[64 * 256];
    __shared__ float sS[NWAVE][448];   // per-wave scratch: hx-copy [n*64+k], d1 [n*33+j]
    __shared__ float sX[NWAVE][80];    // per-wave x_t, flat [n*11+f]
    __shared__ float sA[NWAVE][52];    // per-wave normalized adj, flat [i*7+j]

    const int tid   = threadIdx.x;
    const int lane  = tid & 63;
    const int wv    = tid >> 6;
    const int batch = blockIdx.x * NWAVE + wv;

    // ---- stage gate weights (transposed) into LDS, block-cooperative ----
    for (int i = tid; i < 16384; i += NT) {
        int c = i >> 6, k = i & 63;                 // c = gate row (g*64+h), k = col
        int dst = (k << 8) + ((c & 63) << 2) + (c >> 6);
        sWI[dst] = wih[i];
        sWH[dst] = whh[i];
    }

    float* wS = sS[wv];
    float* wX = sX[wv];
    float* wA = sA[wv];

    // ---- biases into registers (lane-indexed) ----
    float benc = encb[lane];
    float bg1  = g1b[lane];
    float bg2  = g2b[lane];
    float gb0  = bih[lane]       + bhh[lane];
    float gb1  = bih[64 + lane]  + bhh[64 + lane];
    float gb2  = bih[128 + lane] + bhh[128 + lane];
    float gb3  = bih[192 + lane] + bhh[192 + lane];
    float bd1  = d1b[lane & 31];
    const int dn = lane / 6, dd = lane - dn * 6;    // dec2 output mapping (lane<42)
    float bd2  = d2b[lane < 42 ? dd : 0];

    // ---- adjacency normalization (wave-local) ----
    if (lane < 49) {
        int ai = lane / 7, aj = lane - ai * 7;
        float a = adj[(size_t)batch * 49 + lane];
        if (ai == aj) a = 1.0f;
        wA[lane] = a;
    }
    WFENCE();
    if (lane < 49) {
        int ai = lane / 7, aj = lane - ai * 7;
        float si = 0.f, sj = 0.f;
        #pragma unroll
        for (int m = 0; m < 7; ++m) { si += wA[ai * 7 + m]; sj += wA[aj * 7 + m]; }
        si = fmaxf(si, 1.0f); sj = fmaxf(sj, 1.0f);
        float v = wA[lane] / (sqrtf(si) * sqrtf(sj));
        wA[lane] = v;
    }
    WFENCE();
    __syncthreads();   // the only block barrier: gate weights ready

    float hx[7], cx[7], s2[7];
    #pragma unroll
    for (int n = 0; n < 7; ++n) { hx[n] = 0.f; cx[n] = 0.f; }

    const float* xbase = xh + (size_t)batch * (24 * 77);

    auto cell = [&]() {
        // ---- encoder: e[n] = relu(x[n]@Wenc + b), lane = h ----
        float e[7];
        #pragma unroll
        for (int n = 0; n < 7; ++n) e[n] = benc;
        #pragma unroll
        for (int f = 0; f < 11; ++f) {
            float w = encw[(f << 6) + lane];
            #pragma unroll
            for (int n = 0; n < 7; ++n) e[n] = fmaf(wX[n * 11 + f], w, e[n]);
        }
        #pragma unroll
        for (int n = 0; n < 7; ++n) e[n] = fmaxf(e[n], 0.f);
        // ---- gcn1 matmul: y[n] = sum_k e[n][k] * W1[k][lane] ----
        float y[7];
        #pragma unroll
        for (int n = 0; n < 7; ++n) y[n] = 0.f;
        #pragma unroll 8
        for (int k = 0; k < 64; ++k) {
            float w = g1w[(k << 6) + lane];
            #pragma unroll
            for (int n = 0; n < 7; ++n) y[n] = fmaf(rdl(e[n], k), w, y[n]);
        }
        float s1[7];
        #pragma unroll
        for (int n = 0; n < 7; ++n) {
            float a = bg1;
            #pragma unroll
            for (int m = 0; m < 7; ++m) a = fmaf(wA[n * 7 + m], y[m], a);
            s1[n] = fmaxf(a, 0.f);
        }
        // ---- gcn2 ----
        #pragma unroll
        for (int n = 0; n < 7; ++n) y[n] = 0.f;
        #pragma unroll 8
        for (int k = 0; k < 64; ++k) {
            float w = g2w[(k << 6) + lane];
            #pragma unroll
            for (int n = 0; n < 7; ++n) y[n] = fmaf(rdl(s1[n], k), w, y[n]);
        }
        #pragma unroll
        for (int n = 0; n < 7; ++n) {
            float a = bg2;
            #pragma unroll
            for (int m = 0; m < 7; ++m) a = fmaf(wA[n * 7 + m], y[m], a);
            s2[n] = fmaxf(a, 0.f);
        }
        // ---- gates: acc[n][g] = s2@wih^T + hx@whh^T + b ----
        float a0[7], a1[7], a2[7], a3[7];
        #pragma unroll
        for (int n = 0; n < 7; ++n) { a0[n] = gb0; a1[n] = gb1; a2[n] = gb2; a3[n] = gb3; }
        #pragma unroll 16
        for (int k = 0; k < 64; ++k) {
            const float4 wi = *(const float4*)(sWI + (k << 8) + (lane << 2));
            const float4 wh = *(const float4*)(sWH + (k << 8) + (lane << 2));
            #pragma unroll
            for (int n = 0; n < 7; ++n) {
                float sv = rdl(s2[n], k);
                float hv = rdl(hx[n], k);
                a0[n] = fmaf(sv, wi.x, a0[n]); a0[n] = fmaf(hv, wh.x, a0[n]);
                a1[n] = fmaf(sv, wi.y, a1[n]); a1[n] = fmaf(hv, wh.y, a1[n]);
                a2[n] = fmaf(sv, wi.z, a2[n]); a2[n] = fmaf(hv, wh.z, a2[n]);
                a3[n] = fmaf(sv, wi.w, a3[n]); a3[n] = fmaf(hv, wh.w, a3[n]);
            }
        }
        // ---- LSTM pointwise (all local) ----
        #pragma unroll
        for (int n = 0; n < 7; ++n) {
            float iv = sigm(a0[n]);
            float fv = sigm(a1[n]);
            float gv = tanh_f(a2[n]);
            float ov = sigm(a3[n]);
            cx[n] = fmaf(fv, cx[n], iv * gv);
            hx[n] = ov * tanh_f(cx[n]);
        }
    };

    // ---- history scan ----
    #pragma unroll 1
    for (int t = 0; t < 24; ++t) {
        const float* xb = xbase + t * 77;
        wX[lane] = xb[lane];
        if (lane < 13) wX[64 + lane] = xb[64 + lane];
        WFENCE();
        cell();
    }
    // wX now holds the t=23 frame: pred = wX[n*11+0..5], stat = wX[n*11+6..10]

    // ---- autoregressive future scan ----
    float* outb = out + (size_t)batch * (48 * 42);
    #pragma unroll 1
    for (int st = 0; st < 48; ++st) {
        cell();
        // hx -> LDS for decoder broadcast
        #pragma unroll
        for (int n = 0; n < 7; ++n) wS[(n << 6) + lane] = hx[n];
        WFENCE();
        // dec1: lanes 0-31 handle n=0..3, lanes 32-63 handle n=4..6 (slot3 dups n=6)
        const int g = lane >> 5, j = lane & 31;
        float d1v[4];
        #pragma unroll
        for (int slot = 0; slot < 4; ++slot) {
            int n = g ? (slot < 3 ? 4 + slot : 6) : slot;
            float a = bd1;
            #pragma unroll 8
            for (int k = 0; k < 64; ++k)
                a = fmaf(wS[(n << 6) + k], d1w[(k << 5) + j], a);
            d1v[slot] = fmaxf(a, 0.f);
        }
        // d1 transposed into wS at stride 33 (reads above already issued; DS in-order)
        #pragma unroll
        for (int slot = 0; slot < 4; ++slot) {
            int n = g ? (slot < 3 ? 4 + slot : 6) : slot;
            wS[n * 33 + j] = d1v[slot];
        }
        WFENCE();
        // dec2 + residual + clip + store; update pred in wX
        if (lane < 42) {
            float a = bd2;
            #pragma unroll
            for (int jj = 0; jj < 32; ++jj)
                a = fmaf(wS[dn * 33 + jj], d2w[jj * 6 + dd], a);
            float p = wX[dn * 11 + dd] + tanh_f(a) * 0.05f;
            p = fminf(fmaxf(p, 0.f), 1.f);
            wX[dn * 11 + dd] = p;
            outb[st * 42 + lane] = p;
        }
        WFENCE();
    }
}

extern "C" void kernel_launch(void* const* d_in, const int* in_sizes, int n_in,
                              void* d_out, int out_size, void* d_ws, size_t ws_size,
                              hipStream_t stream)
{
    const float* xh   = (const float*)d_in[0];
    const float* adjp = (const float*)d_in[1];
    const float* encw = (const float*)d_in[2];
    const float* encb = (const float*)d_in[3];
    const float* g1w  = (const float*)d_in[4];
    const float* g1b  = (const float*)d_in[5];
    const float* g2w  = (const float*)d_in[6];
    const float* g2b  = (const float*)d_in[7];
    const float* wih  = (const float*)d_in[8];
    const float* whh  = (const float*)d_in[9];
    const float* bih  = (const float*)d_in[10];
    const float* bhh  = (const float*)d_in[11];
    const float* d1w  = (const float*)d_in[12];
    const float* d1b  = (const float*)d_in[13];
    const float* d2w  = (const float*)d_in[14];
    const float* d2b  = (const float*)d_in[15];
    float* out = (float*)d_out;

    hipLaunchKernelGGL(stgnn, dim3(GRID), dim3(NT), 0, stream,
                       xh, adjp, encw, encb, g1w, g1b, g2w, g2b,
                       wih, whh, bih, bhh, d1w, d1b, d2w, d2b, out);
}

// Round 3
// 3037.686 us; speedup vs baseline: 2.9575x; 1.5214x over previous
//
#include <hip/hip_runtime.h>
#include <math.h>

#define NT    512
#define NWAVE 8
#define GRID  512   // 4096 batches / 8 per block

typedef float v2f __attribute__((ext_vector_type(2)));
typedef float v4f __attribute__((ext_vector_type(4)));

#define L2E 1.44269504089f
__device__ __forceinline__ float fexp2(float x) { return __builtin_amdgcn_exp2f(x); }
__device__ __forceinline__ float frcp(float x)  { return __builtin_amdgcn_rcpf(x); }
// sigmoid(x) = 1/(1+2^(-x*log2e)); tanh(x) = 1 - 2/(2^(2x*log2e)+1)  (graceful at +-inf)
__device__ __forceinline__ float fsigm(float x) { return frcp(1.0f + fexp2(-L2E * x)); }
__device__ __forceinline__ float ftanh_(float x){ return 1.0f - 2.0f * frcp(fexp2((2.0f*L2E) * x) + 1.0f); }
__device__ __forceinline__ v2f pkfma(v2f a, v2f b, v2f c) { return __builtin_elementwise_fma(a, b, c); }
// wave-local LDS write->read ordering (DS pipe is in-order per wave; clobber stops compiler reorder)
#define WFENCE() asm volatile("s_waitcnt lgkmcnt(0)" ::: "memory")

__global__ __launch_bounds__(NT, 2)
void stgnn(const float* __restrict__ xh,   const float* __restrict__ adj,
           const float* __restrict__ encw, const float* __restrict__ encb,
           const float* __restrict__ g1w,  const float* __restrict__ g1b,
           const float* __restrict__ g2w,  const float* __restrict__ g2b,
           const float* __restrict__ wih,  const float* __restrict__ whh,
           const float* __restrict__ bih,  const float* __restrict__ bhh,
           const float* __restrict__ d1w,  const float* __restrict__ d1b,
           const float* __restrict__ d2w,  const float* __restrict__ d2b,
           float* __restrict__ out)
{
    // pool layout (floats):
    //   [0, 32768):  gate weights, [q<16][m<2][c<256][4] at ((q*2+m)<<10) + (c<<2)
    //   [32768 + wv*1024): per-wave scratch: Ab 448 (e/s1/s2/d1), Bb 448 (hx),
    //                      Xb 77 (x_t), Aj 49 (norm adj)       -> exactly 160 KiB total
    __shared__ float pool[40960];

    const int tid  = threadIdx.x;
    const int lane = tid & 63;
    const int wv   = tid >> 6;
    const int batch = blockIdx.x * NWAVE + wv;

    // ---- stage gate weights into LDS, k-quad layout, block-cooperative ----
    for (int i = tid; i < 8192; i += NT) {
        int m = i >> 12, id = i & 4095, c = id >> 4, q = id & 15;
        const float* src = (m ? whh : wih) + (c << 6) + (q << 2);
        *(v4f*)&pool[((q * 2 + m) << 10) + (c << 2)] = *(const v4f*)src;
    }

    float* WP = pool + 32768 + (wv << 10);
    float* Ab = WP;          // activations (e / s1 / s2 / dec-hidden), rows [n][64]
    float* Bb = WP + 448;    // hx rows [n][64]
    float* Xb = WP + 896;    // x_t flat [n*11+f]
    float* Aj = WP + 973;    // normalized adjacency flat [i*7+j]

    // ---- biases into registers ----
    float benc = encb[lane];
    float bg1  = g1b[lane];
    float bg2  = g2b[lane];
    float gb0  = bih[lane]       + bhh[lane];
    float gb1  = bih[64 + lane]  + bhh[64 + lane];
    float gb2  = bih[128 + lane] + bhh[128 + lane];
    float gb3  = bih[192 + lane] + bhh[192 + lane];
    float bd1  = d1b[lane & 31];
    const int dn = lane / 6, dd = lane - dn * 6;
    float bd2  = d2b[lane < 42 ? dd : 0];

    // ---- adjacency normalization (wave-local, one-time) ----
    if (lane < 49) {
        int ai = lane / 7, ja = lane - ai * 7;
        float a = adj[(size_t)batch * 49 + lane];
        if (ai == ja) a = 1.0f;
        Aj[lane] = a;
    }
    WFENCE();
    float anorm = 0.0f;
    if (lane < 49) {
        int ai = lane / 7, ja = lane - ai * 7;
        float si = 0.f, sj = 0.f;
        #pragma unroll
        for (int m = 0; m < 7; ++m) { si += Aj[ai * 7 + m]; sj += Aj[ja * 7 + m]; }
        si = fmaxf(si, 1.0f); sj = fmaxf(sj, 1.0f);
        anorm = Aj[lane] / (sqrtf(si) * sqrtf(sj));
    }
    WFENCE();
    if (lane < 49) Aj[lane] = anorm;
    // zero hx
    #pragma unroll
    for (int n = 0; n < 7; ++n) Bb[(n << 6) + lane] = 0.0f;
    WFENCE();
    __syncthreads();   // gate weights ready

    float cx[7];
    #pragma unroll
    for (int n = 0; n < 7; ++n) cx[n] = 0.0f;

    const float* xbase = xh + (size_t)batch * (24 * 77);

    auto cell = [&]() {
        // ---- encoder: e[n][lane] = relu(x[n] @ Wenc + b); stage into Ab ----
        {
            float e[7];
            #pragma unroll
            for (int n = 0; n < 7; ++n) e[n] = benc;
            #pragma unroll
            for (int f = 0; f < 11; ++f) {
                float w = encw[(f << 6) + lane];
                #pragma unroll
                for (int n = 0; n < 7; ++n) e[n] = fmaf(Xb[n * 11 + f], w, e[n]);
            }
            #pragma unroll
            for (int n = 0; n < 7; ++n) Ab[(n << 6) + lane] = fmaxf(e[n], 0.0f);
        }
        WFENCE();
        float s[7];   // mixed activations (s1 then s2), per-lane (lane = h)
        // ---- gcn1 matmul + mix ----
        {
            float y[7] = {0,0,0,0,0,0,0};
            #pragma unroll 4
            for (int q = 0; q < 16; ++q) {
                float w0 = g1w[((4*q+0) << 6) + lane];
                float w1 = g1w[((4*q+1) << 6) + lane];
                float w2 = g1w[((4*q+2) << 6) + lane];
                float w3 = g1w[((4*q+3) << 6) + lane];
                #pragma unroll
                for (int n = 0; n < 7; ++n) {
                    v4f eq = *(const v4f*)&Ab[(n << 6) + (q << 2)];
                    y[n] = fmaf(eq.x, w0, fmaf(eq.y, w1, fmaf(eq.z, w2, fmaf(eq.w, w3, y[n]))));
                }
            }
            #pragma unroll
            for (int n = 0; n < 7; ++n) {
                float a = bg1;
                #pragma unroll
                for (int m = 0; m < 7; ++m) a = fmaf(Aj[n * 7 + m], y[m], a);
                s[n] = fmaxf(a, 0.0f);
            }
            #pragma unroll
            for (int n = 0; n < 7; ++n) Ab[(n << 6) + lane] = s[n];   // WAR: DS in-order
        }
        WFENCE();
        // ---- gcn2 matmul + mix ----
        {
            float y[7] = {0,0,0,0,0,0,0};
            #pragma unroll 4
            for (int q = 0; q < 16; ++q) {
                float w0 = g2w[((4*q+0) << 6) + lane];
                float w1 = g2w[((4*q+1) << 6) + lane];
                float w2 = g2w[((4*q+2) << 6) + lane];
                float w3 = g2w[((4*q+3) << 6) + lane];
                #pragma unroll
                for (int n = 0; n < 7; ++n) {
                    v4f sq = *(const v4f*)&Ab[(n << 6) + (q << 2)];
                    y[n] = fmaf(sq.x, w0, fmaf(sq.y, w1, fmaf(sq.z, w2, fmaf(sq.w, w3, y[n]))));
                }
            }
            #pragma unroll
            for (int n = 0; n < 7; ++n) {
                float a = bg2;
                #pragma unroll
                for (int m = 0; m < 7; ++m) a = fmaf(Aj[n * 7 + m], y[m], a);
                s[n] = fmaxf(a, 0.0f);
            }
            #pragma unroll
            for (int n = 0; n < 7; ++n) Ab[(n << 6) + lane] = s[n];
        }
        WFENCE();
        // ---- gates: pk_fma along k; lane owns columns {lane, 64+lane, 128+lane, 192+lane} ----
        {
            v2f A0[7], A1[7], A2[7], A3[7];
            #pragma unroll
            for (int n = 0; n < 7; ++n) { A0[n] = (v2f)0.f; A1[n] = (v2f)0.f; A2[n] = (v2f)0.f; A3[n] = (v2f)0.f; }
            #pragma unroll 2
            for (int q = 0; q < 16; ++q) {
                const int wb = (q << 11) + (lane << 2);
                v4f wi0 = *(const v4f*)&pool[wb];
                v4f wi1 = *(const v4f*)&pool[wb + 256];
                v4f wi2 = *(const v4f*)&pool[wb + 512];
                v4f wi3 = *(const v4f*)&pool[wb + 768];
                v4f wh0 = *(const v4f*)&pool[wb + 1024];
                v4f wh1 = *(const v4f*)&pool[wb + 1280];
                v4f wh2 = *(const v4f*)&pool[wb + 1536];
                v4f wh3 = *(const v4f*)&pool[wb + 1792];
                #pragma unroll
                for (int n = 0; n < 7; ++n) {
                    v4f sq = *(const v4f*)&Ab[(n << 6) + (q << 2)];
                    v4f hq = *(const v4f*)&Bb[(n << 6) + (q << 2)];
                    A0[n] = pkfma(sq.xy, wi0.xy, A0[n]); A0[n] = pkfma(sq.zw, wi0.zw, A0[n]);
                    A1[n] = pkfma(sq.xy, wi1.xy, A1[n]); A1[n] = pkfma(sq.zw, wi1.zw, A1[n]);
                    A2[n] = pkfma(sq.xy, wi2.xy, A2[n]); A2[n] = pkfma(sq.zw, wi2.zw, A2[n]);
                    A3[n] = pkfma(sq.xy, wi3.xy, A3[n]); A3[n] = pkfma(sq.zw, wi3.zw, A3[n]);
                    A0[n] = pkfma(hq.xy, wh0.xy, A0[n]); A0[n] = pkfma(hq.zw, wh0.zw, A0[n]);
                    A1[n] = pkfma(hq.xy, wh1.xy, A1[n]); A1[n] = pkfma(hq.zw, wh1.zw, A1[n]);
                    A2[n] = pkfma(hq.xy, wh2.xy, A2[n]); A2[n] = pkfma(hq.zw, wh2.zw, A2[n]);
                    A3[n] = pkfma(hq.xy, wh3.xy, A3[n]); A3[n] = pkfma(hq.zw, wh3.zw, A3[n]);
                }
            }
            // ---- LSTM pointwise; hx -> Bb (WAR on Bb is safe: DS in-order) ----
            #pragma unroll
            for (int n = 0; n < 7; ++n) {
                float iv = fsigm(A0[n].x + A0[n].y + gb0);
                float fv = fsigm(A1[n].x + A1[n].y + gb1);
                float gv = ftanh_(A2[n].x + A2[n].y + gb2);
                float ov = fsigm(A3[n].x + A3[n].y + gb3);
                float c  = fmaf(fv, cx[n], iv * gv);
                cx[n] = c;
                Bb[(n << 6) + lane] = ov * ftanh_(c);
            }
        }
        WFENCE();
    };

    // ---- history scan ----
    #pragma unroll 1
    for (int t = 0; t < 24; ++t) {
        const float* xb = xbase + t * 77;
        Xb[lane < 77 ? lane : 0] = xb[lane < 77 ? lane : 0];
        if (lane < 13) Xb[64 + lane] = xb[64 + lane];
        WFENCE();
        cell();
    }
    // Xb holds the t=23 frame: pred = Xb[n*11+0..5], stat = Xb[n*11+6..10]

    // ---- autoregressive future scan ----
    float* outb = out + (size_t)batch * (48 * 42);
    #pragma unroll 1
    for (int st = 0; st < 48; ++st) {
        cell();
        // dec1: lanes 0-31 rows n=0..3, lanes 32-63 rows n=4..6 (slot3 dups n=6)
        const int g = lane >> 5, j = lane & 31;
        float d1v[4];
        #pragma unroll
        for (int slot = 0; slot < 4; ++slot) {
            int n = g ? (slot < 3 ? 4 + slot : 6) : slot;
            float a = bd1;
            #pragma unroll 4
            for (int q = 0; q < 16; ++q) {
                v4f hq = *(const v4f*)&Bb[(n << 6) + (q << 2)];
                a = fmaf(hq.x, d1w[((4*q+0) << 5) + j],
                    fmaf(hq.y, d1w[((4*q+1) << 5) + j],
                    fmaf(hq.z, d1w[((4*q+2) << 5) + j],
                    fmaf(hq.w, d1w[((4*q+3) << 5) + j], a))));
            }
            d1v[slot] = fmaxf(a, 0.0f);
        }
        #pragma unroll
        for (int slot = 0; slot < 4; ++slot) {
            int n = g ? (slot < 3 ? 4 + slot : 6) : slot;
            Ab[n * 33 + j] = d1v[slot];      // stride 33: conflict-free dec2 reads
        }
        WFENCE();
        // dec2 + residual + clip + store; update pred in Xb
        if (lane < 42) {
            float a = bd2;
            #pragma unroll 8
            for (int jj = 0; jj < 32; ++jj)
                a = fmaf(Ab[dn * 33 + jj], d2w[jj * 6 + dd], a);
            float p = Xb[dn * 11 + dd] + ftanh_(a) * 0.05f;
            p = fminf(fmaxf(p, 0.0f), 1.0f);
            Xb[dn * 11 + dd] = p;
            outb[st * 42 + lane] = p;
        }
        WFENCE();
    }
}

extern "C" void kernel_launch(void* const* d_in, const int* in_sizes, int n_in,
                              void* d_out, int out_size, void* d_ws, size_t ws_size,
                              hipStream_t stream)
{
    const float* xh   = (const float*)d_in[0];
    const float* adjp = (const float*)d_in[1];
    const float* encw = (const float*)d_in[2];
    const float* encb = (const float*)d_in[3];
    const float* g1w  = (const float*)d_in[4];
    const float* g1b  = (const float*)d_in[5];
    const float* g2w  = (const float*)d_in[6];
    const float* g2b  = (const float*)d_in[7];
    const float* wih  = (const float*)d_in[8];
    const float* whh  = (const float*)d_in[9];
    const float* bih  = (const float*)d_in[10];
    const float* bhh  = (const float*)d_in[11];
    const float* d1w  = (const float*)d_in[12];
    const float* d1b  = (const float*)d_in[13];
    const float* d2w  = (const float*)d_in[14];
    const float* d2b  = (const float*)d_in[15];
    float* out = (float*)d_out;

    hipLaunchKernelGGL(stgnn, dim3(GRID), dim3(NT), 0, stream,
                       xh, adjp, encw, encb, g1w, g1b, g2w, g2b,
                       wih, whh, bih, bhh, d1w, d1b, d2w, d2b, out);
}